// Round 14
// baseline (53.431 us; speedup 1.0000x reference)
//
#include <hip/hip_runtime.h>

typedef unsigned short u16;
typedef unsigned int u32;
typedef __bf16 bf16x8 __attribute__((ext_vector_type(8)));
typedef float f32x16 __attribute__((ext_vector_type(16)));
typedef const void __attribute__((address_space(1))) gvoid;
typedef void __attribute__((address_space(3))) lvoid;

#define GLOAD16(gp, lp) __builtin_amdgcn_global_load_lds((gvoid*)(gp), (lvoid*)(lp), 16, 0, 0)
#define POST_BARRIER_FENCE() do { __builtin_amdgcn_sched_barrier(0); asm volatile("" ::: "memory"); } while (0)

namespace {
constexpr int Ln = 2048;
constexpr float EPS = 1e-8f;
}

__device__ __forceinline__ u32 pk2(float lo, float hi) {
    u32 r;
    asm("v_cvt_pk_bf16_f32 %0, %1, %2" : "=v"(r) : "v"(lo), "v"(hi));
    return r;
}

// half_swap semantics: na[l<32] = b[l+32], na[l>=32] = a[l];
//                      nb[l<32] = b[l],    nb[l>=32] = a[l-32]
__device__ __forceinline__ void half_swap(u32 a, u32 b, u32& na, u32& nb) {
    u32 sa = (u32)__shfl_xor((int)a, 32, 64);
    u32 sb = (u32)__shfl_xor((int)b, 32, 64);
    int hi = (threadIdx.x & 63) >> 5;
    na = hi ? a : sb;
    nb = hi ? sa : b;
}

// ---------------- Kernel 1: projections via MFMA, no LDS (R13, passed) -----
__global__ __launch_bounds__(128) void proj_k(
    const float* __restrict__ x,
    const float* __restrict__ Bw, const float* __restrict__ Bb,
    const float* __restrict__ Cw, const float* __restrict__ Cb,
    const float* __restrict__ Vw, const float* __restrict__ Vb,
    u16* __restrict__ BZh, u16* __restrict__ CZh, u16* __restrict__ VZTh)
{
    const int tid = threadIdx.x;
    const int ln = tid & 31;
    const int g5 = (tid >> 5) & 1;
    const int w  = tid >> 6;                      // 0..1
    const int row0 = blockIdx.x * 64 + w * 32;
    const int b   = row0 >> 11;
    const int l0b = row0 & 2047;

    bf16x8 wf[3][2][4];
    const float* const Wp[3] = {Bw, Cw, Vw};
    #pragma unroll
    for (int m = 0; m < 3; ++m)
      #pragma unroll
      for (int e = 0; e < 2; ++e)
        #pragma unroll
        for (int c = 0; c < 4; ++c) {
            const float* p = Wp[m] + (e * 32 + ln) * 64 + c * 16 + g5 * 8;
            const float4 lo = *(const float4*)p;
            const float4 hi = *(const float4*)(p + 4);
            uint4 t4;
            t4.x = pk2(lo.x, lo.y); t4.y = pk2(lo.z, lo.w);
            t4.z = pk2(hi.x, hi.y); t4.w = pk2(hi.z, hi.w);
            wf[m][e][c] = __builtin_bit_cast(bf16x8, t4);
        }
    bf16x8 xf[4];
    {
        const float* xp = x + (row0 + ln) * 64 + g5 * 8;
        #pragma unroll
        for (int c = 0; c < 4; ++c) {
            const float4 lo = *(const float4*)(xp + c * 16);
            const float4 hi = *(const float4*)(xp + c * 16 + 4);
            uint4 t4;
            t4.x = pk2(lo.x, lo.y); t4.y = pk2(lo.z, lo.w);
            t4.z = pk2(hi.x, hi.y); t4.w = pk2(hi.z, hi.w);
            xf[c] = __builtin_bit_cast(bf16x8, t4);
        }
    }
    const float* const biasBC[2] = {Bb, Cb};
    u16* const outBC[2] = {BZh, CZh};
    #pragma unroll
    for (int m = 0; m < 2; ++m) {
        #pragma unroll
        for (int e = 0; e < 2; ++e) {
            f32x16 st;
            #pragma unroll
            for (int q = 0; q < 4; ++q) {
                const float4 bv = *(const float4*)(biasBC[m] + e * 32 + q * 8 + g5 * 4);
                st[q*4+0] = bv.x; st[q*4+1] = bv.y; st[q*4+2] = bv.z; st[q*4+3] = bv.w;
            }
            #pragma unroll
            for (int c = 0; c < 4; ++c)
                st = __builtin_amdgcn_mfma_f32_32x32x16_bf16(wf[m][e][c], xf[c], st, 0, 0, 0);
            u16* op = outBC[m] + (row0 + ln) * 64 + e * 32 + g5 * 4;
            #pragma unroll
            for (int q = 0; q < 4; ++q) {
                uint2 pk;
                pk.x = pk2(st[q*4+0], st[q*4+1]);
                pk.y = pk2(st[q*4+2], st[q*4+3]);
                *(uint2*)(op + q * 8) = pk;
            }
        }
    }
    #pragma unroll
    for (int e = 0; e < 2; ++e) {
        const float vb = Vb[e * 32 + ln];
        f32x16 st;
        #pragma unroll
        for (int r = 0; r < 16; ++r) st[r] = vb;
        #pragma unroll
        for (int c = 0; c < 4; ++c)
            st = __builtin_amdgcn_mfma_f32_32x32x16_bf16(xf[c], wf[2][e][c], st, 0, 0, 0);
        u16* op = VZTh + (b * 64 + e * 32 + ln) * Ln + l0b + g5 * 4;
        #pragma unroll
        for (int q = 0; q < 4; ++q) {
            uint2 pk;
            pk.x = pk2(st[q*4+0], st[q*4+1]);
            pk.y = pk2(st[q*4+2], st[q*4+3]);
            *(uint2*)(op + q * 8) = pk;
        }
    }
}

// ---------------- Kernel 2: barrier-free denom, operands direct ------------
// denp[half][b][m] = sum over l-half of relu(BZ[b,l,:] . CZ[b,m,:]).
// Grid (32 m-tiles, 8 b, 2 halves) = 512 blocks -> 2 blocks/CU; no LDS in
// main loop, no barriers: 16 free-running waves/CU hide all L2 latency.
// Structure = R7's denom (correctness-verified), re-gridded to l-halves.
__global__ __launch_bounds__(512) void denom_k(
    const u16* __restrict__ BZh, const u16* __restrict__ CZh,
    float* __restrict__ denp)
{
    __shared__ float red[64][5];
    const int tid = threadIdx.x;
    const int lane = tid & 63;
    const int ln = lane & 31;
    const int g5 = lane >> 5;
    const int w = tid >> 6;
    const int wm2 = w & 1, wl4 = w >> 1;      // 2 m-halves x 4 l-subtiles
    const int flat = (int)blockIdx.z * 256 + (int)blockIdx.y * 32 + (int)blockIdx.x;
    const int nf = (flat & 7) * 64 + (flat >> 3);   // XCD<->batch swizzle
    const int b = nf >> 6;
    const int rem = nf & 63;
    const int mb = (rem & 31) * 64;
    const int half = rem >> 5;
    const int l0h = half * 1024;

    // A-fragments: CZ rows (m) direct from global (L2-hot)
    bf16x8 af[4];
    {
        const u16* cp = CZh + ((b * Ln + mb + wm2 * 32 + ln) << 6) + g5 * 8;
        #pragma unroll
        for (int c = 0; c < 4; ++c) af[c] = *(const bf16x8*)(cp + c * 16);
    }
    // B-fragments: BZ rows (l) direct; register double-buffer 1 chunk ahead
    const u16* const bp0 = BZh + ((b * Ln + l0h + wl4 * 32 + ln) << 6) + g5 * 8;
    auto loadB = [&](int it, bf16x8* dst) {
        const u16* bp = bp0 + ((it * 128) << 6);
        #pragma unroll
        for (int c = 0; c < 4; ++c) dst[c] = *(const bf16x8*)(bp + c * 16);
    };
    bf16x8 bF[2][4];
    loadB(0, bF[0]);
    float accs[16];
    #pragma unroll
    for (int r = 0; r < 16; ++r) accs[r] = 0.f;
    #pragma unroll
    for (int it = 0; it < 8; ++it) {
        const int cur = it & 1;
        if (it < 7) loadB(it + 1, bF[cur ^ 1]);
        f32x16 st = {};
        __builtin_amdgcn_s_setprio(1);
        #pragma unroll
        for (int c = 0; c < 4; ++c)
            st = __builtin_amdgcn_mfma_f32_32x32x16_bf16(af[c], bF[cur][c], st, 0, 0, 0);
        __builtin_amdgcn_s_setprio(0);
        #pragma unroll
        for (int r = 0; r < 16; ++r) accs[r] += fmaxf(st[r], 0.f);
    }
    // reduce over the 32 l-columns held across lanes of each half
    #pragma unroll
    for (int msk = 1; msk <= 16; msk <<= 1)
        #pragma unroll
        for (int r = 0; r < 16; ++r)
            accs[r] += __shfl_xor(accs[r], msk, 64);
    if (ln == 0) {
        #pragma unroll
        for (int r = 0; r < 16; ++r) {
            const int moff = (r & 3) + ((r >> 2) << 3) + g5 * 4;
            red[wm2 * 32 + moff][wl4] = accs[r];
        }
    }
    __syncthreads();
    if (tid < 64)
        denp[(half * 8 + b) * Ln + mb + tid] =
            red[tid][0] + red[tid][1] + red[tid][2] + red[tid][3];
}

// ---------------- Kernel 3: 128-m chunks, 2x32K dbuf, 2 blocks/CU (R13) ----
__global__ __launch_bounds__(512, 4) void fused_out(
    const float* __restrict__ x,
    const u16* __restrict__ BZh, const u16* __restrict__ CZh,
    const u16* __restrict__ VZTh, const float* __restrict__ denp,
    float* __restrict__ out)
{
    // [0,8K) denl | [8K,72K) 2x32K stage bufs; epilogue red (55296B) in bufs
    __shared__ __attribute__((aligned(16))) char smem[73728];
    float* const denl = (float*)smem;
    char* const bufs = smem + 8192;
    const int tid = threadIdx.x;
    const int lane = tid & 63;
    const int ln = lane & 31;
    const int g5 = lane >> 5;
    const int w = tid >> 6;
    const int wm = w & 3;       // m-subtile (K-split for phase B)
    const int wl = w >> 2;      // l-half
    const int bx = (int)blockIdx.x;
    const int nf = (bx & 7) * 32 + (bx >> 3);   // XCD<->batch locality swizzle
    const int b = nf >> 5;
    const int l0 = (nf & 31) * 64;
    const int wave_base = tid & ~63;
    const int mA = wm * 32 + ln;

    auto stage = [&](int t) {              // 128-m chunk: CZ [128m][64d] + VZT [64d][128m]
        char* bufc = bufs + (t & 1) * 32768;
        char* vzb = bufc + 16384;
        const int m0s = t << 7;
        #pragma unroll
        for (int it = 0; it < 2; ++it) {
            int j = (it << 9) + tid;
            int r = j >> 3;
            int u = (j & 7) ^ (r & 7);
            GLOAD16(CZh + ((b * Ln + m0s + r) << 6) + (u << 3),
                    bufc + ((it << 9) + wave_base) * 16);
        }
        #pragma unroll
        for (int it = 0; it < 2; ++it) {
            int j = (it << 9) + tid;
            int r = j >> 4;
            int u = (j & 15) ^ (r & 7);
            GLOAD16(VZTh + ((b << 6) + r) * Ln + m0s + (u << 3),
                    vzb + ((it << 9) + wave_base) * 16);
        }
    };

    // prologue: stage(0), denominators, BZ fragments direct
    stage(0);
    {
        const float4 c0 = *(const float4*)(denp + b * Ln + tid * 4);
        const float4 c1 = *(const float4*)(denp + (8 + b) * Ln + tid * 4);
        float4 dv;
        dv.x = 1.f / (c0.x + c1.x + EPS);
        dv.y = 1.f / (c0.y + c1.y + EPS);
        dv.z = 1.f / (c0.z + c1.z + EPS);
        dv.w = 1.f / (c0.w + c1.w + EPS);
        *(float4*)(denl + tid * 4) = dv;
    }
    bf16x8 bzf[4];
    {
        const u16* bp = BZh + ((b * Ln + l0 + wl * 32 + ln) << 6) + g5 * 8;
        #pragma unroll
        for (int c = 0; c < 4; ++c) bzf[c] = *(const bf16x8*)(bp + c * 16);
    }
    __syncthreads();                       // drains vmcnt: buf0 staged, denl ready

    f32x16 acc0 = {}, acc1 = {};
    for (int t = 0; t < 16; ++t) {
        if (t > 0) {
            asm volatile("s_waitcnt vmcnt(0)" ::: "memory");   // stage(t) landed
            __builtin_amdgcn_s_barrier();                      // all waves done with buf[(t-1)&1]
            POST_BARRIER_FENCE();
        }
        if (t + 1 < 16) stage(t + 1);
        const char* cz = bufs + (t & 1) * 32768;
        const char* vz = cz + 16384;
        // ---- phase A: st[m][l] = CZ . BZ^T ----
        f32x16 st = {};
        __builtin_amdgcn_s_setprio(1);
        #pragma unroll
        for (int c = 0; c < 4; ++c) {
            int un = (c << 1) | g5;
            bf16x8 a = *(const bf16x8*)(cz + (mA << 7) + ((un ^ (mA & 7)) << 4));
            st = __builtin_amdgcn_mfma_f32_32x32x16_bf16(a, bzf[c], st, 0, 0, 0);
        }
        __builtin_amdgcn_s_setprio(0);
        // ---- relu, scale by 1/den, pack ----
        const int mq0 = (t << 7) + wm * 32;
        u32 wv[8];
        #pragma unroll
        for (int q = 0; q < 4; ++q) {
            const float4 dq = *(const float4*)(denl + mq0 + q * 8 + g5 * 4);
            float p0 = fmaxf(st[q*4+0], 0.f) * dq.x;
            float p1 = fmaxf(st[q*4+1], 0.f) * dq.y;
            float p2 = fmaxf(st[q*4+2], 0.f) * dq.z;
            float p3 = fmaxf(st[q*4+3], 0.f) * dq.w;
            wv[q*2+0] = pk2(p0, p1);
            wv[q*2+1] = pk2(p2, p3);
        }
        // ---- assemble PV B-fragments in-register ----
        u32 f0w0, f0w1, f0w2, f0w3, f1w0, f1w1, f1w2, f1w3;
        half_swap(wv[2], wv[0], f0w2, f0w0);
        half_swap(wv[3], wv[1], f0w3, f0w1);
        half_swap(wv[6], wv[4], f1w2, f1w0);
        half_swap(wv[7], wv[5], f1w3, f1w1);
        bf16x8 pf0, pf1;
        { uint4 t4; t4.x=f0w0; t4.y=f0w1; t4.z=f0w2; t4.w=f0w3; pf0 = __builtin_bit_cast(bf16x8, t4); }
        { uint4 t4; t4.x=f1w0; t4.y=f1w1; t4.z=f1w2; t4.w=f1w3; pf1 = __builtin_bit_cast(bf16x8, t4); }
        // ---- phase B: accT[d][l] += VZT . P over this wave's 32-m slice ----
        const int un00 = (wm << 2) | g5;            // c16 = 0
        const int un01 = (wm << 2) | 2 | g5;        // c16 = 1
        __builtin_amdgcn_s_setprio(1);
        {
            bf16x8 av;
            av = *(const bf16x8*)(vz + (ln << 8) + ((un00 ^ (ln & 7)) << 4));
            acc0 = __builtin_amdgcn_mfma_f32_32x32x16_bf16(av, pf0, acc0, 0, 0, 0);
            av = *(const bf16x8*)(vz + (ln << 8) + ((un01 ^ (ln & 7)) << 4));
            acc0 = __builtin_amdgcn_mfma_f32_32x32x16_bf16(av, pf1, acc0, 0, 0, 0);
            av = *(const bf16x8*)(vz + ((32 + ln) << 8) + ((un00 ^ (ln & 7)) << 4));
            acc1 = __builtin_amdgcn_mfma_f32_32x32x16_bf16(av, pf0, acc1, 0, 0, 0);
            av = *(const bf16x8*)(vz + ((32 + ln) << 8) + ((un01 ^ (ln & 7)) << 4));
            acc1 = __builtin_amdgcn_mfma_f32_32x32x16_bf16(av, pf1, acc1, 0, 0, 0);
        }
        __builtin_amdgcn_s_setprio(0);
    }

    // ---- epilogue: cross-wm reduction (6 slots in bufs) + direct store ----
    __syncthreads();                    // all LDS reads done; bufs dead
    float* red = (float*)bufs;
    constexpr int LSTR = 36;            // floats per lane slot (144B, bank-rotating)
    constexpr int SSTR = 64 * LSTR;     // 9216B per slot; 6 slots = 55296B < 64K
    if (wm >= 2) {
        float* base = red + (wl * 2 + (wm - 2)) * SSTR + lane * LSTR;
        #pragma unroll
        for (int r = 0; r < 16; ++r) { base[r] = acc0[r]; base[16 + r] = acc1[r]; }
    }
    __syncthreads();
    if (wm < 2) {
        float* base = red + (wl * 2 + wm) * SSTR + lane * LSTR;
        #pragma unroll
        for (int r = 0; r < 16; ++r) { acc0[r] += base[r]; acc1[r] += base[16 + r]; }
    }
    __syncthreads();
    if (wm == 1) {
        float* base = red + (4 + wl) * SSTR + lane * LSTR;
        #pragma unroll
        for (int r = 0; r < 16; ++r) { base[r] = acc0[r]; base[16 + r] = acc1[r]; }
    }
    __syncthreads();
    if (wm == 0) {
        float* base = red + (4 + wl) * SSTR + lane * LSTR;
        #pragma unroll
        for (int r = 0; r < 16; ++r) { acc0[r] += base[r]; acc1[r] += base[16 + r]; }
        const int row = b * Ln + l0 + wl * 32 + ln;
        #pragma unroll
        for (int q = 0; q < 4; ++q) {
            const int d0 = q * 8 + g5 * 4;
            const float4 x0 = *(const float4*)(x + row * 64 + d0);
            float4 o0;
            o0.x = x0.x + acc0[q*4+0]; o0.y = x0.y + acc0[q*4+1];
            o0.z = x0.z + acc0[q*4+2]; o0.w = x0.w + acc0[q*4+3];
            *(float4*)(out + row * 64 + d0) = o0;
            const float4 x1 = *(const float4*)(x + row * 64 + 32 + d0);
            float4 o1;
            o1.x = x1.x + acc1[q*4+0]; o1.y = x1.y + acc1[q*4+1];
            o1.z = x1.z + acc1[q*4+2]; o1.w = x1.w + acc1[q*4+3];
            *(float4*)(out + row * 64 + 32 + d0) = o1;
        }
    }
}

extern "C" void kernel_launch(void* const* d_in, const int* in_sizes, int n_in,
                              void* d_out, int out_size, void* d_ws, size_t ws_size,
                              hipStream_t stream) {
    const float* x  = (const float*)d_in[0];
    const float* Bw = (const float*)d_in[1];
    const float* Bb = (const float*)d_in[2];
    const float* Cw = (const float*)d_in[3];
    const float* Cb = (const float*)d_in[4];
    const float* Vw = (const float*)d_in[5];
    const float* Vb = (const float*)d_in[6];
    float* out = (float*)d_out;
    char* wsb = (char*)d_ws;
    u16* BZh  = (u16*)wsb;                       // 2 MB
    u16* CZh  = (u16*)(wsb + (2u << 20));        // 2 MB
    u16* VZTh = (u16*)(wsb + (4u << 20));        // 2 MB
    float* denp = (float*)(wsb + (6u << 20));    // 128 KB: [2][8][2048]

    proj_k<<<dim3(256), 128, 0, stream>>>(x, Bw, Bb, Cw, Cb, Vw, Vb, BZh, CZh, VZTh);
    denom_k<<<dim3(32, 8, 2), 512, 0, stream>>>(BZh, CZh, denp);
    fused_out<<<dim3(256), 512, 0, stream>>>(x, BZh, CZh, VZTh, denp, out);
}

// Round 15
// 46.999 us; speedup vs baseline: 1.1369x; 1.1369x over previous
//
#include <hip/hip_runtime.h>

typedef unsigned short u16;
typedef unsigned int u32;
typedef __bf16 bf16x8 __attribute__((ext_vector_type(8)));
typedef float f32x16 __attribute__((ext_vector_type(16)));
typedef const void __attribute__((address_space(1))) gvoid;
typedef void __attribute__((address_space(3))) lvoid;

#define GLOAD16(gp, lp) __builtin_amdgcn_global_load_lds((gvoid*)(gp), (lvoid*)(lp), 16, 0, 0)
#define POST_BARRIER_FENCE() do { __builtin_amdgcn_sched_barrier(0); asm volatile("" ::: "memory"); } while (0)

namespace {
constexpr int Ln = 2048;
constexpr float EPS = 1e-8f;
}

__device__ __forceinline__ u32 pk2(float lo, float hi) {
    u32 r;
    asm("v_cvt_pk_bf16_f32 %0, %1, %2" : "=v"(r) : "v"(lo), "v"(hi));
    return r;
}

// half_swap semantics: na[l<32] = b[l+32], na[l>=32] = a[l];
//                      nb[l<32] = b[l],    nb[l>=32] = a[l-32]
__device__ __forceinline__ void half_swap(u32 a, u32 b, u32& na, u32& nb) {
    u32 sa = (u32)__shfl_xor((int)a, 32, 64);
    u32 sb = (u32)__shfl_xor((int)b, 32, 64);
    int hi = (threadIdx.x & 63) >> 5;
    na = hi ? a : sb;
    nb = hi ? sa : b;
}

// ---------------- Kernel 1: projections via MFMA, no LDS (R13, passed) -----
__global__ __launch_bounds__(128) void proj_k(
    const float* __restrict__ x,
    const float* __restrict__ Bw, const float* __restrict__ Bb,
    const float* __restrict__ Cw, const float* __restrict__ Cb,
    const float* __restrict__ Vw, const float* __restrict__ Vb,
    u16* __restrict__ BZh, u16* __restrict__ CZh, u16* __restrict__ VZTh)
{
    const int tid = threadIdx.x;
    const int ln = tid & 31;
    const int g5 = (tid >> 5) & 1;
    const int w  = tid >> 6;                      // 0..1
    const int row0 = blockIdx.x * 64 + w * 32;
    const int b   = row0 >> 11;
    const int l0b = row0 & 2047;

    bf16x8 wf[3][2][4];
    const float* const Wp[3] = {Bw, Cw, Vw};
    #pragma unroll
    for (int m = 0; m < 3; ++m)
      #pragma unroll
      for (int e = 0; e < 2; ++e)
        #pragma unroll
        for (int c = 0; c < 4; ++c) {
            const float* p = Wp[m] + (e * 32 + ln) * 64 + c * 16 + g5 * 8;
            const float4 lo = *(const float4*)p;
            const float4 hi = *(const float4*)(p + 4);
            uint4 t4;
            t4.x = pk2(lo.x, lo.y); t4.y = pk2(lo.z, lo.w);
            t4.z = pk2(hi.x, hi.y); t4.w = pk2(hi.z, hi.w);
            wf[m][e][c] = __builtin_bit_cast(bf16x8, t4);
        }
    bf16x8 xf[4];
    {
        const float* xp = x + (row0 + ln) * 64 + g5 * 8;
        #pragma unroll
        for (int c = 0; c < 4; ++c) {
            const float4 lo = *(const float4*)(xp + c * 16);
            const float4 hi = *(const float4*)(xp + c * 16 + 4);
            uint4 t4;
            t4.x = pk2(lo.x, lo.y); t4.y = pk2(lo.z, lo.w);
            t4.z = pk2(hi.x, hi.y); t4.w = pk2(hi.z, hi.w);
            xf[c] = __builtin_bit_cast(bf16x8, t4);
        }
    }
    const float* const biasBC[2] = {Bb, Cb};
    u16* const outBC[2] = {BZh, CZh};
    #pragma unroll
    for (int m = 0; m < 2; ++m) {
        #pragma unroll
        for (int e = 0; e < 2; ++e) {
            f32x16 st;
            #pragma unroll
            for (int q = 0; q < 4; ++q) {
                const float4 bv = *(const float4*)(biasBC[m] + e * 32 + q * 8 + g5 * 4);
                st[q*4+0] = bv.x; st[q*4+1] = bv.y; st[q*4+2] = bv.z; st[q*4+3] = bv.w;
            }
            #pragma unroll
            for (int c = 0; c < 4; ++c)
                st = __builtin_amdgcn_mfma_f32_32x32x16_bf16(wf[m][e][c], xf[c], st, 0, 0, 0);
            u16* op = outBC[m] + (row0 + ln) * 64 + e * 32 + g5 * 4;
            #pragma unroll
            for (int q = 0; q < 4; ++q) {
                uint2 pk;
                pk.x = pk2(st[q*4+0], st[q*4+1]);
                pk.y = pk2(st[q*4+2], st[q*4+3]);
                *(uint2*)(op + q * 8) = pk;
            }
        }
    }
    #pragma unroll
    for (int e = 0; e < 2; ++e) {
        const float vb = Vb[e * 32 + ln];
        f32x16 st;
        #pragma unroll
        for (int r = 0; r < 16; ++r) st[r] = vb;
        #pragma unroll
        for (int c = 0; c < 4; ++c)
            st = __builtin_amdgcn_mfma_f32_32x32x16_bf16(xf[c], wf[2][e][c], st, 0, 0, 0);
        u16* op = VZTh + (b * 64 + e * 32 + ln) * Ln + l0b + g5 * 4;
        #pragma unroll
        for (int q = 0; q < 4; ++q) {
            uint2 pk;
            pk.x = pk2(st[q*4+0], st[q*4+1]);
            pk.y = pk2(st[q*4+2], st[q*4+3]);
            *(uint2*)(op + q * 8) = pk;
        }
    }
}

// ---------------- Kernel 2: per-wave-private staged denom, zero barriers ----
// denp[half][b][m] = sum over l-half of relu(BZ[b,l,:] . CZ[b,m,:]).
// Grid (32,8,2) = 512 blocks -> 2 blocks/CU. Each wave owns a private
// 2x4KB LDS double-buffer and 256 l-rows (8 chunks x 32); staging via
// global_load_lds synced ONLY by the wave's own vmcnt/lgkmcnt -> no
// inter-wave barriers in the main loop; 16 decoupled waves/CU hide drains.
__global__ __launch_bounds__(512) void denom_k(
    const u16* __restrict__ BZh, const u16* __restrict__ CZh,
    float* __restrict__ denp)
{
    __shared__ __attribute__((aligned(16))) char smem2[65536 + 1536];
    float (*red)[5] = (float(*)[5])(smem2 + 65536);
    const int tid = threadIdx.x;
    const int lane = tid & 63;
    const int ln = lane & 31;
    const int g5 = lane >> 5;
    const int w = tid >> 6;
    const int wm2 = w & 1, wl4 = w >> 1;      // 2 m-halves x 4 l-subtiles
    const int flat = (int)blockIdx.z * 256 + (int)blockIdx.y * 32 + (int)blockIdx.x;
    const int nf = (flat & 7) * 64 + (flat >> 3);   // XCD<->batch swizzle
    const int b = nf >> 6;
    const int rem = nf & 63;
    const int mb = (rem & 31) * 64;
    const int half = rem >> 5;
    const int l0w = half * 1024 + wl4 * 256;  // this wave's 256-row l-range
    char* const bufw = smem2 + w * 8192;      // private 2x4KB

    // A-fragments: CZ rows (m) direct from global (L2-hot)
    bf16x8 af[4];
    {
        const u16* cp = CZh + ((b * Ln + mb + wm2 * 32 + ln) << 6) + g5 * 8;
        #pragma unroll
        for (int c = 0; c < 4; ++c) af[c] = *(const bf16x8*)(cp + c * 16);
    }
    asm volatile("s_waitcnt vmcnt(0)" ::: "memory");   // af resident
    POST_BARRIER_FENCE();

    // stage chunk c (32 rows, 4KB) into private buf[c&1]
    auto stageW = [&](int c) {
        const int base = b * Ln + l0w + c * 32;
        #pragma unroll
        for (int it = 0; it < 4; ++it) {
            int r = it * 8 + (lane >> 3);
            int u = (lane & 7) ^ (r & 7);
            GLOAD16(BZh + ((base + r) << 6) + (u << 3),
                    bufw + (c & 1) * 4096 + it * 1024);
        }
    };
    stageW(0); stageW(1);                     // 8 outstanding

    float accs[16];
    #pragma unroll
    for (int r = 0; r < 16; ++r) accs[r] = 0.f;
    #pragma unroll 1
    for (int c = 0; c < 8; ++c) {
        asm volatile("s_waitcnt vmcnt(4)" ::: "memory");  // buf[c&1] staged
        POST_BARRIER_FENCE();
        const char* bc = bufw + (c & 1) * 4096;
        bf16x8 bfr[4];
        #pragma unroll
        for (int c2 = 0; c2 < 4; ++c2) {
            int un = (c2 << 1) | g5;
            bfr[c2] = *(const bf16x8*)(bc + (ln << 7) + ((un ^ (ln & 7)) << 4));
        }
        asm volatile("s_waitcnt lgkmcnt(0)" ::: "memory");  // bfr in regs
        POST_BARRIER_FENCE();
        if (c + 2 < 8) stageW(c + 2);          // safe: overwrites the buf just read
        f32x16 st = {};
        __builtin_amdgcn_s_setprio(1);
        #pragma unroll
        for (int c2 = 0; c2 < 4; ++c2)
            st = __builtin_amdgcn_mfma_f32_32x32x16_bf16(af[c2], bfr[c2], st, 0, 0, 0);
        __builtin_amdgcn_s_setprio(0);
        #pragma unroll
        for (int r = 0; r < 16; ++r) accs[r] += fmaxf(st[r], 0.f);
    }
    // reduce over the 32 l-columns held across lanes
    #pragma unroll
    for (int msk = 1; msk <= 16; msk <<= 1)
        #pragma unroll
        for (int r = 0; r < 16; ++r)
            accs[r] += __shfl_xor(accs[r], msk, 64);
    if (ln == 0) {
        #pragma unroll
        for (int r = 0; r < 16; ++r) {
            const int moff = (r & 3) + ((r >> 2) << 3) + g5 * 4;
            red[wm2 * 32 + moff][wl4] = accs[r];
        }
    }
    __syncthreads();                           // only barrier in the kernel
    if (tid < 64)
        denp[(half * 8 + b) * Ln + mb + tid] =
            red[tid][0] + red[tid][1] + red[tid][2] + red[tid][3];
}

// ---------------- Kernel 3: 128-m chunks, 2x32K dbuf, 2 blocks/CU (R13) ----
__global__ __launch_bounds__(512, 4) void fused_out(
    const float* __restrict__ x,
    const u16* __restrict__ BZh, const u16* __restrict__ CZh,
    const u16* __restrict__ VZTh, const float* __restrict__ denp,
    float* __restrict__ out)
{
    // [0,8K) denl | [8K,72K) 2x32K stage bufs; epilogue red (55296B) in bufs
    __shared__ __attribute__((aligned(16))) char smem[73728];
    float* const denl = (float*)smem;
    char* const bufs = smem + 8192;
    const int tid = threadIdx.x;
    const int lane = tid & 63;
    const int ln = lane & 31;
    const int g5 = lane >> 5;
    const int w = tid >> 6;
    const int wm = w & 3;       // m-subtile (K-split for phase B)
    const int wl = w >> 2;      // l-half
    const int bx = (int)blockIdx.x;
    const int nf = (bx & 7) * 32 + (bx >> 3);   // XCD<->batch locality swizzle
    const int b = nf >> 5;
    const int l0 = (nf & 31) * 64;
    const int wave_base = tid & ~63;
    const int mA = wm * 32 + ln;

    auto stage = [&](int t) {              // 128-m chunk: CZ [128m][64d] + VZT [64d][128m]
        char* bufc = bufs + (t & 1) * 32768;
        char* vzb = bufc + 16384;
        const int m0s = t << 7;
        #pragma unroll
        for (int it = 0; it < 2; ++it) {
            int j = (it << 9) + tid;
            int r = j >> 3;
            int u = (j & 7) ^ (r & 7);
            GLOAD16(CZh + ((b * Ln + m0s + r) << 6) + (u << 3),
                    bufc + ((it << 9) + wave_base) * 16);
        }
        #pragma unroll
        for (int it = 0; it < 2; ++it) {
            int j = (it << 9) + tid;
            int r = j >> 4;
            int u = (j & 15) ^ (r & 7);
            GLOAD16(VZTh + ((b << 6) + r) * Ln + m0s + (u << 3),
                    vzb + ((it << 9) + wave_base) * 16);
        }
    };

    // prologue: stage(0), denominators, BZ fragments direct
    stage(0);
    {
        const float4 c0 = *(const float4*)(denp + b * Ln + tid * 4);
        const float4 c1 = *(const float4*)(denp + (8 + b) * Ln + tid * 4);
        float4 dv;
        dv.x = 1.f / (c0.x + c1.x + EPS);
        dv.y = 1.f / (c0.y + c1.y + EPS);
        dv.z = 1.f / (c0.z + c1.z + EPS);
        dv.w = 1.f / (c0.w + c1.w + EPS);
        *(float4*)(denl + tid * 4) = dv;
    }
    bf16x8 bzf[4];
    {
        const u16* bp = BZh + ((b * Ln + l0 + wl * 32 + ln) << 6) + g5 * 8;
        #pragma unroll
        for (int c = 0; c < 4; ++c) bzf[c] = *(const bf16x8*)(bp + c * 16);
    }
    __syncthreads();                       // drains vmcnt: buf0 staged, denl ready

    f32x16 acc0 = {}, acc1 = {};
    for (int t = 0; t < 16; ++t) {
        if (t > 0) {
            asm volatile("s_waitcnt vmcnt(0)" ::: "memory");   // stage(t) landed
            __builtin_amdgcn_s_barrier();                      // all waves done with buf[(t-1)&1]
            POST_BARRIER_FENCE();
        }
        if (t + 1 < 16) stage(t + 1);
        const char* cz = bufs + (t & 1) * 32768;
        const char* vz = cz + 16384;
        // ---- phase A: st[m][l] = CZ . BZ^T ----
        f32x16 st = {};
        __builtin_amdgcn_s_setprio(1);
        #pragma unroll
        for (int c = 0; c < 4; ++c) {
            int un = (c << 1) | g5;
            bf16x8 a = *(const bf16x8*)(cz + (mA << 7) + ((un ^ (mA & 7)) << 4));
            st = __builtin_amdgcn_mfma_f32_32x32x16_bf16(a, bzf[c], st, 0, 0, 0);
        }
        __builtin_amdgcn_s_setprio(0);
        // ---- relu, scale by 1/den, pack ----
        const int mq0 = (t << 7) + wm * 32;
        u32 wv[8];
        #pragma unroll
        for (int q = 0; q < 4; ++q) {
            const float4 dq = *(const float4*)(denl + mq0 + q * 8 + g5 * 4);
            float p0 = fmaxf(st[q*4+0], 0.f) * dq.x;
            float p1 = fmaxf(st[q*4+1], 0.f) * dq.y;
            float p2 = fmaxf(st[q*4+2], 0.f) * dq.z;
            float p3 = fmaxf(st[q*4+3], 0.f) * dq.w;
            wv[q*2+0] = pk2(p0, p1);
            wv[q*2+1] = pk2(p2, p3);
        }
        // ---- assemble PV B-fragments in-register ----
        u32 f0w0, f0w1, f0w2, f0w3, f1w0, f1w1, f1w2, f1w3;
        half_swap(wv[2], wv[0], f0w2, f0w0);
        half_swap(wv[3], wv[1], f0w3, f0w1);
        half_swap(wv[6], wv[4], f1w2, f1w0);
        half_swap(wv[7], wv[5], f1w3, f1w1);
        bf16x8 pf0, pf1;
        { uint4 t4; t4.x=f0w0; t4.y=f0w1; t4.z=f0w2; t4.w=f0w3; pf0 = __builtin_bit_cast(bf16x8, t4); }
        { uint4 t4; t4.x=f1w0; t4.y=f1w1; t4.z=f1w2; t4.w=f1w3; pf1 = __builtin_bit_cast(bf16x8, t4); }
        // ---- phase B: accT[d][l] += VZT . P over this wave's 32-m slice ----
        const int un00 = (wm << 2) | g5;            // c16 = 0
        const int un01 = (wm << 2) | 2 | g5;        // c16 = 1
        __builtin_amdgcn_s_setprio(1);
        {
            bf16x8 av;
            av = *(const bf16x8*)(vz + (ln << 8) + ((un00 ^ (ln & 7)) << 4));
            acc0 = __builtin_amdgcn_mfma_f32_32x32x16_bf16(av, pf0, acc0, 0, 0, 0);
            av = *(const bf16x8*)(vz + (ln << 8) + ((un01 ^ (ln & 7)) << 4));
            acc0 = __builtin_amdgcn_mfma_f32_32x32x16_bf16(av, pf1, acc0, 0, 0, 0);
            av = *(const bf16x8*)(vz + ((32 + ln) << 8) + ((un00 ^ (ln & 7)) << 4));
            acc1 = __builtin_amdgcn_mfma_f32_32x32x16_bf16(av, pf0, acc1, 0, 0, 0);
            av = *(const bf16x8*)(vz + ((32 + ln) << 8) + ((un01 ^ (ln & 7)) << 4));
            acc1 = __builtin_amdgcn_mfma_f32_32x32x16_bf16(av, pf1, acc1, 0, 0, 0);
        }
        __builtin_amdgcn_s_setprio(0);
    }

    // ---- epilogue: cross-wm reduction (6 slots in bufs) + direct store ----
    __syncthreads();                    // all LDS reads done; bufs dead
    float* red = (float*)bufs;
    constexpr int LSTR = 36;            // floats per lane slot (144B, bank-rotating)
    constexpr int SSTR = 64 * LSTR;     // 9216B per slot; 6 slots = 55296B < 64K
    if (wm >= 2) {
        float* base = red + (wl * 2 + (wm - 2)) * SSTR + lane * LSTR;
        #pragma unroll
        for (int r = 0; r < 16; ++r) { base[r] = acc0[r]; base[16 + r] = acc1[r]; }
    }
    __syncthreads();
    if (wm < 2) {
        float* base = red + (wl * 2 + wm) * SSTR + lane * LSTR;
        #pragma unroll
        for (int r = 0; r < 16; ++r) { acc0[r] += base[r]; acc1[r] += base[16 + r]; }
    }
    __syncthreads();
    if (wm == 1) {
        float* base = red + (4 + wl) * SSTR + lane * LSTR;
        #pragma unroll
        for (int r = 0; r < 16; ++r) { base[r] = acc0[r]; base[16 + r] = acc1[r]; }
    }
    __syncthreads();
    if (wm == 0) {
        float* base = red + (4 + wl) * SSTR + lane * LSTR;
        #pragma unroll
        for (int r = 0; r < 16; ++r) { acc0[r] += base[r]; acc1[r] += base[16 + r]; }
        const int row = b * Ln + l0 + wl * 32 + ln;
        #pragma unroll
        for (int q = 0; q < 4; ++q) {
            const int d0 = q * 8 + g5 * 4;
            const float4 x0 = *(const float4*)(x + row * 64 + d0);
            float4 o0;
            o0.x = x0.x + acc0[q*4+0]; o0.y = x0.y + acc0[q*4+1];
            o0.z = x0.z + acc0[q*4+2]; o0.w = x0.w + acc0[q*4+3];
            *(float4*)(out + row * 64 + d0) = o0;
            const float4 x1 = *(const float4*)(x + row * 64 + 32 + d0);
            float4 o1;
            o1.x = x1.x + acc1[q*4+0]; o1.y = x1.y + acc1[q*4+1];
            o1.z = x1.z + acc1[q*4+2]; o1.w = x1.w + acc1[q*4+3];
            *(float4*)(out + row * 64 + 32 + d0) = o1;
        }
    }
}

extern "C" void kernel_launch(void* const* d_in, const int* in_sizes, int n_in,
                              void* d_out, int out_size, void* d_ws, size_t ws_size,
                              hipStream_t stream) {
    const float* x  = (const float*)d_in[0];
    const float* Bw = (const float*)d_in[1];
    const float* Bb = (const float*)d_in[2];
    const float* Cw = (const float*)d_in[3];
    const float* Cb = (const float*)d_in[4];
    const float* Vw = (const float*)d_in[5];
    const float* Vb = (const float*)d_in[6];
    float* out = (float*)d_out;
    char* wsb = (char*)d_ws;
    u16* BZh  = (u16*)wsb;                       // 2 MB
    u16* CZh  = (u16*)(wsb + (2u << 20));        // 2 MB
    u16* VZTh = (u16*)(wsb + (4u << 20));        // 2 MB
    float* denp = (float*)(wsb + (6u << 20));    // 128 KB: [2][8][2048]

    proj_k<<<dim3(256), 128, 0, stream>>>(x, Bw, Bb, Cw, Cb, Vw, Vb, BZh, CZh, VZTh);
    denom_k<<<dim3(32, 8, 2), 512, 0, stream>>>(BZh, CZh, denp);
    fused_out<<<dim3(256), 512, 0, stream>>>(x, BZh, CZh, VZTh, denp, out);
}